// Round 12
// baseline (89.473 us; speedup 1.0000x reference)
//
#include <hip/hip_runtime.h>
#include <math.h>

#define WS 21
#define KWIN 43            // 2*WS+1
#define H 128
#define W 128
#define B 2
#define C 3
#define HW (H * W)
#define CHW (C * H * W)
#define NPIX (B * H * W)   // 32768
#define SIGMA_SPACE (1.0f / 98.0f)
#define NSPLIT 16
#define SQ_THR_FP16 0.17f  // fp16-screen threshold (validated r7-r11, absmax ~0)
#define NEG_SC_LOG2E 72.1347520445f   // 50*log2(e)
#define SG 17.509290f      // sum_{k=-21..21} exp(-k^2/98)
#define WSLOTS 172         // wave-private slice: even[0..85] + odd[86..171] (uint2)

typedef _Float16 h2_t __attribute__((ext_vector_type(2)));

// Compiler-only fence: wave-private LDS relies on HW per-wave DS ordering; this
// stops compiler reordering of lane-local LDS ops whose cross-lane aliasing it
// cannot see (r10 bug -> r11 fix, validated absmax 1.0 -> 0.0).
#define LDS_COMPILER_FENCE() asm volatile("" ::: "memory")

__device__ __forceinline__ int reflect_idx(int t, int n) {
    if (t < 0) t = -t;
    if (t > n - 1) t = 2 * (n - 1) - t;
    return t;
}

// ---------------- K1: H-pass conv (256 thr) + Sobel mask (128 thr) + out zero ----------------
__global__ __launch_bounds__(384)
void prep_kernel(const float* __restrict__ orig,
                 const float* __restrict__ smooth,
                 float* __restrict__ Gh, float* __restrict__ Qh,
                 float* __restrict__ mask, float* __restrict__ out) {
    __shared__ float row[170], rsq[170], wt[KWIN];
    const int bid = blockIdx.x;      // bc*128 + h ; bc = b*3+c
    const int h   = bid & 127;
    const int bc  = bid >> 7;
    const int t   = threadIdx.x;
    if (bid == 0 && t == 0) out[0] = 0.f;
    if (t < KWIN) { int k = t - WS; wt[t] = __expf(-SIGMA_SPACE * (float)(k * k)); }
    const float* src = smooth + bc * HW + h * W;
    if (t < 170) {
        float v = src[reflect_idx(t - WS, W)];
        row[t] = v; rsq[t] = v * v;
    }
    __syncthreads();
    if (t < 256) {
        const int w = t & 127;
        const float* buf = (t < 128) ? row : rsq;
        float acc = 0.f;
#pragma unroll
        for (int y = 0; y < KWIN; ++y) acc = fmaf(wt[y], buf[w + y], acc);
        ((t < 128) ? Gh : Qh)[bid * W + w] = acc;
    } else if (bc == 0 || bc == 3) {
        const int b = bc / 3;
        const int w = t - 256;
        const float* ob = orig   + b * CHW;
        const float* sb = smooth + b * CHW;
        int hm = reflect_idx(h - 1, H), hp = reflect_idx(h + 1, H);
        int wm = reflect_idx(w - 1, W), wp = reflect_idx(w + 1, W);
        float eo = 0.f, es = 0.f;
#pragma unroll
        for (int c = 0; c < C; ++c) {
            const float* po = ob + c * HW;
            const float* ps = sb + c * HW;
            {
                float a00 = po[hm * W + wm], a01 = po[hm * W + w], a02 = po[hm * W + wp];
                float a10 = po[h  * W + wm],                        a12 = po[h  * W + wp];
                float a20 = po[hp * W + wm], a21 = po[hp * W + w], a22 = po[hp * W + wp];
                float gx = (a02 - a00) + 2.f * (a12 - a10) + (a22 - a20);
                float gy = (a20 - a00) + 2.f * (a21 - a01) + (a22 - a02);
                eo += sqrtf(gx * gx + gy * gy);
            }
            {
                float a00 = ps[hm * W + wm], a01 = ps[hm * W + w], a02 = ps[hm * W + wp];
                float a10 = ps[h  * W + wm],                        a12 = ps[h  * W + wp];
                float a20 = ps[hp * W + wm], a21 = ps[hp * W + w], a22 = ps[hp * W + wp];
                float gx = (a02 - a00) + 2.f * (a12 - a10) + (a22 - a20);
                float gy = (a20 - a00) + 2.f * (a21 - a01) + (a22 - a02);
                es += sqrtf(gx * gx + gy * gy);
            }
        }
        float m = ((eo < 20.0f) && ((es - eo) > 10.0f)) ? 1.0f : 0.0f;
        mask[(b << 14) + (h << 7) + w] = m;
    }
}

// ---- K2: barrier-free wave-private screen, 2 centers/thread, even/odd LDS split ----
__global__ __launch_bounds__(256)
void screen_kernel(const float* __restrict__ orig,
                   const float* __restrict__ smooth,
                   const float* __restrict__ Gh, const float* __restrict__ Qh,
                   const float* __restrict__ mask,
                   float* __restrict__ out) {
    __shared__ uint2 oA[4 * WSLOTS];    // 4 wave-private slices
    __shared__ float red[4];

    const int t    = threadIdx.x;
    const int wave = t >> 6;
    const int lane = t & 63;
    const int gw   = blockIdx.x * 4 + wave;   // [0, 4096)
    const int split = gw & 15;                // xi-slice
    const int h     = (gw >> 4) & 127;
    const int b     = gw >> 11;
    const int w0    = lane * 2;               // two centers: w0, w0+1
    const int wb    = wave * WSLOTS;

    const float* ob  = orig   + b * CHW;
    const float* sb  = smooth + b * CHW;
    const float* GhB = Gh + b * 3 * HW;
    const float* QhB = Qh + b * 3 * HW;

    // ---- per-center constants (two centers, all scalars -- no arrays) ----
    float2 mm = ((const float2*)(mask + (b << 14) + (h << 7)))[lane];
    const float thr0 = (mm.x == 0.0f) ? SQ_THR_FP16 : -1.0f;
    const float thr1 = (mm.y == 0.0f) ? SQ_THR_FP16 : -1.0f;

    float2 o0 = ((const float2*)(ob + h * W))[lane];
    float2 o1 = ((const float2*)(ob + HW + h * W))[lane];
    float2 o2 = ((const float2*)(ob + 2 * HW + h * W))[lane];
    float2 s0 = ((const float2*)(sb + h * W))[lane];
    float2 s1 = ((const float2*)(sb + HW + h * W))[lane];
    float2 s2 = ((const float2*)(sb + 2 * HW + h * W))[lane];

    const h2_t c01h0 = { (_Float16)o0.x, (_Float16)o1.x };
    const h2_t c2xh0 = { (_Float16)o2.x, (_Float16)0.f };
    const h2_t c01h1 = { (_Float16)o0.y, (_Float16)o1.y };
    const h2_t c2xh1 = { (_Float16)o2.y, (_Float16)0.f };

    // AL constants per center
    const float n00 = o0.x * 0.f + s0.x * s0.x * SG, n01 = s1.x * s1.x * SG, n02 = s2.x * s2.x * SG;
    const float n10 = s0.y * s0.y * SG, n11 = s1.y * s1.y * SG, n12 = s2.y * s2.y * SG;
    const float tc00 = -2.f * s0.x, tc01 = -2.f * s1.x, tc02 = -2.f * s2.x;
    const float tc10 = -2.f * s0.y, tc11 = -2.f * s1.y, tc12 = -2.f * s2.y;

    // ---- staging descriptors: lane owns e = lane, lane+64, lane+128 (if lane<42) ----
    const int  e0 = lane,      i0 = (e0 & 1) * 86 + (e0 >> 1);
    const int  e1 = lane + 64, i1 = (e1 & 1) * 86 + (e1 >> 1);
    const bool has2 = (lane < 42);
    const int  e2 = lane + 128, i2 = (e2 & 1) * 86 + (e2 >> 1);
    const int  sA_ = reflect_idx(e0 - WS, W);
    const int  sB_ = reflect_idx(e1 - WS, W);
    const int  sC_ = reflect_idx(e2 - WS, W);

    float accAL0 = 0.f, accAL1 = 0.f, accS = 0.f;

    // ---- prologue: prefetch staging for first xi ----
    float A0, A1, A2, B0, B1, B2, C0 = 0.f, C1 = 0.f, C2_ = 0.f;
    {
        const int rr0 = reflect_idx(h + split - WS, H);
        const float* prow = ob + rr0 * W;
        A0 = prow[sA_]; A1 = prow[HW + sA_]; A2 = prow[2 * HW + sA_];
        B0 = prow[sB_]; B1 = prow[HW + sB_]; B2 = prow[2 * HW + sB_];
        if (has2) { C0 = prow[sC_]; C1 = prow[HW + sC_]; C2_ = prow[2 * HW + sC_]; }
    }

    const uint2* pE = oA + wb + lane;        // even-e section, immediate offsets
    const uint2* pO = oA + wb + 86 + lane;   // odd-e section

    for (int xi = split; xi < KWIN; xi += NSPLIT) {
        const int x  = xi - WS;
        const int rr = reflect_idx(h + x, H);        // wave-uniform source row

        LDS_COMPILER_FENCE();
        {   // write this xi's staged row (regs from prefetch)
            h2_t v01 = { (_Float16)A0, (_Float16)A1 };
            h2_t v2x = { (_Float16)A2, (_Float16)0.f };
            oA[wb + i0] = make_uint2(__builtin_bit_cast(unsigned, v01),
                                     __builtin_bit_cast(unsigned, v2x));
            h2_t u01 = { (_Float16)B0, (_Float16)B1 };
            h2_t u2x = { (_Float16)B2, (_Float16)0.f };
            oA[wb + i1] = make_uint2(__builtin_bit_cast(unsigned, u01),
                                     __builtin_bit_cast(unsigned, u2x));
            if (has2) {
                h2_t y01 = { (_Float16)C0, (_Float16)C1 };
                h2_t y2x = { (_Float16)C2_, (_Float16)0.f };
                oA[wb + i2] = make_uint2(__builtin_bit_cast(unsigned, y01),
                                         __builtin_bit_cast(unsigned, y2x));
            }
        }
        LDS_COMPILER_FENCE();

        // prefetch next xi's staged row (no barrier in the way)
        const int xin = xi + NSPLIT;
        if (xin < KWIN) {
            const int rrn = reflect_idx(h + xin - WS, H);
            const float* prow = ob + rrn * W;
            A0 = prow[sA_]; A1 = prow[HW + sA_]; A2 = prow[2 * HW + sA_];
            B0 = prow[sB_]; B1 = prow[HW + sB_]; B2 = prow[2 * HW + sB_];
            if (has2) { C0 = prow[sC_]; C1 = prow[HW + sC_]; C2_ = prow[2 * HW + sC_]; }
        }

        // fused AL term for both pixels at this xi (float2 loads)
        {
            float2 G0 = ((const float2*)(GhB + rr * W))[lane];
            float2 G1 = ((const float2*)(GhB + HW + rr * W))[lane];
            float2 G2 = ((const float2*)(GhB + 2 * HW + rr * W))[lane];
            float2 Q0 = ((const float2*)(QhB + rr * W))[lane];
            float2 Q1 = ((const float2*)(QhB + HW + rr * W))[lane];
            float2 Q2 = ((const float2*)(QhB + 2 * HW + rr * W))[lane];
            float xf = (float)x;
            float wtx = __expf(-SIGMA_SPACE * xf * xf);
            float g0 = (n00 + fmaf(tc00, G0.x, Q0.x))
                     + (n01 + fmaf(tc01, G1.x, Q1.x))
                     + (n02 + fmaf(tc02, G2.x, Q2.x));
            float g1 = (n10 + fmaf(tc10, G0.y, Q0.y))
                     + (n11 + fmaf(tc11, G1.y, Q1.y))
                     + (n12 + fmaf(tc12, G2.y, Q2.y));
            accAL0 = fmaf(wtx, g0, accAL0);
            accAL1 = fmaf(wtx, g1, accAL1);
        }

        // ---- branchless fp16 screen: 44 reads serve 86 (center,yi) pairs ----
        unsigned mA0 = 0u, mB0 = 0u, mA1 = 0u, mB1 = 0u;
#pragma unroll
        for (int i = 0; i < 44; ++i) {
            uint2 vv = (i & 1) ? pO[i >> 1] : pE[i >> 1];   // immediate-offset ds_read_b64
            h2_t p01 = __builtin_bit_cast(h2_t, vv.x);
            h2_t p2x = __builtin_bit_cast(h2_t, vv.y);
            if (i <= 42) {                  // center0, yi = i
                h2_t d01 = c01h0 - p01;
                h2_t d2x = c2xh0 - p2x;
                float sq = __builtin_amdgcn_fdot2(d01, d01,
                            __builtin_amdgcn_fdot2(d2x, d2x, 0.f, false), false);
                unsigned bit = (sq < thr0) ? 1u : 0u;
                if (i < 21) mA0 |= bit << (20 - i);
                else        mB0 |= bit << (42 - i);
            }
            if (i >= 1) {                   // center1, yi = i-1
                const int yi = i - 1;
                h2_t d01 = c01h1 - p01;
                h2_t d2x = c2xh1 - p2x;
                float sq = __builtin_amdgcn_fdot2(d01, d01,
                            __builtin_amdgcn_fdot2(d2x, d2x, 0.f, false), false);
                unsigned bit = (sq < thr1) ? 1u : 0u;
                if (yi < 21) mA1 |= bit << (20 - yi);
                else         mB1 |= bit << (42 - yi);
            }
        }
        if (xi == WS) { mB0 &= ~(1u << 21); mB1 &= ~(1u << 21); }   // self-pairs = 0

        // ---- immediate consumption: exact fp32 recompute from global (L2-resident) ----
        while (mA0 | mB0) {
            int yi;
            if (mA0) { int p = __builtin_ctz(mA0); mA0 &= mA0 - 1; yi = 20 - p; }
            else     { int p = __builtin_ctz(mB0); mB0 &= mB0 - 1; yi = 42 - p; }
            int ww = reflect_idx(w0 + yi - WS, W);
            int a = rr * W + ww;
            float on0 = ob[a], on1 = ob[HW + a], on2 = ob[2 * HW + a];
            float sn0 = sb[a], sn1 = sb[HW + a], sn2 = sb[2 * HW + a];
            float g0 = o0.x - on0, g1 = o1.x - on1, g2 = o2.x - on2;
            float sq = fmaf(g0, g0, fmaf(g1, g1, g2 * g2));
            float tt = -NEG_SC_LOG2E * sq;
            float d0 = fabsf(s0.x - sn0), d1 = fabsf(s1.x - sn1), d2 = fabsf(s2.x - sn2);
            accS += __builtin_amdgcn_exp2f(fmaf(0.8f, __builtin_amdgcn_logf(d0), tt))
                  + __builtin_amdgcn_exp2f(fmaf(0.8f, __builtin_amdgcn_logf(d1), tt))
                  + __builtin_amdgcn_exp2f(fmaf(0.8f, __builtin_amdgcn_logf(d2), tt));
        }
        while (mA1 | mB1) {
            int yi;
            if (mA1) { int p = __builtin_ctz(mA1); mA1 &= mA1 - 1; yi = 20 - p; }
            else     { int p = __builtin_ctz(mB1); mB1 &= mB1 - 1; yi = 42 - p; }
            int ww = reflect_idx(w0 + 1 + yi - WS, W);
            int a = rr * W + ww;
            float on0 = ob[a], on1 = ob[HW + a], on2 = ob[2 * HW + a];
            float sn0 = sb[a], sn1 = sb[HW + a], sn2 = sb[2 * HW + a];
            float g0 = o0.y - on0, g1 = o1.y - on1, g2 = o2.y - on2;
            float sq = fmaf(g0, g0, fmaf(g1, g1, g2 * g2));
            float tt = -NEG_SC_LOG2E * sq;
            float d0 = fabsf(s0.y - sn0), d1 = fabsf(s1.y - sn1), d2 = fabsf(s2.y - sn2);
            accS += __builtin_amdgcn_exp2f(fmaf(0.8f, __builtin_amdgcn_logf(d0), tt))
                  + __builtin_amdgcn_exp2f(fmaf(0.8f, __builtin_amdgcn_logf(d1), tt))
                  + __builtin_amdgcn_exp2f(fmaf(0.8f, __builtin_amdgcn_logf(d2), tt));
        }
        LDS_COMPILER_FENCE();
    }

    float r = mm.x * accAL0 + mm.y * accAL1 + accS;
#pragma unroll
    for (int off = 32; off > 0; off >>= 1) r += __shfl_down(r, off, 64);
    if (lane == 0) red[wave] = r;
    __syncthreads();                               // only barrier in the kernel
    if (t == 0) atomicAdd(out, (red[0] + red[1] + red[2] + red[3]) * (1.0f / (float)NPIX));
}

extern "C" void kernel_launch(void* const* d_in, const int* in_sizes, int n_in,
                              void* d_out, int out_size, void* d_ws, size_t ws_size,
                              hipStream_t stream) {
    const float* orig   = (const float*)d_in[0];
    const float* smooth = (const float*)d_in[1];
    float* out = (float*)d_out;

    float* Gh  = (float*)d_ws;                   // 98304 floats
    float* Qh  = Gh + B * C * HW;                // 98304 floats
    float* msk = Qh + B * C * HW;                // 32768 floats

    prep_kernel<<<B * C * H, 384, 0, stream>>>(orig, smooth, Gh, Qh, msk, out);
    // 4096 waves = B * H * NSPLIT(16); 4 waves/block -> 1024 blocks
    screen_kernel<<<(B * H * NSPLIT) / 4, 256, 0, stream>>>(orig, smooth, Gh, Qh, msk, out);
}